// Round 1
// baseline (109.091 us; speedup 1.0000x reference)
//
#include <hip/hip_runtime.h>

#define T_STEPS 20
#define BT 16
#define TILES 2
#define NTHREADS 512

typedef _Float16 half8 __attribute__((ext_vector_type(8)));
typedef float f32x4 __attribute__((ext_vector_type(4)));

__device__ __forceinline__ float fast_sig(float z) {
    return __builtin_amdgcn_rcpf(1.0f + __expf(-z));
}
__device__ __forceinline__ float fast_tanh(float z) {
    return 1.0f - 2.0f * __builtin_amdgcn_rcpf(1.0f + __expf(2.0f * z));
}

extern "C" __global__ __launch_bounds__(NTHREADS, 2)
void stacked_lstm_kernel(const float* __restrict__ x,
                         const float* __restrict__ Wih1, const float* __restrict__ Whh1,
                         const float* __restrict__ bih1, const float* __restrict__ bhh1,
                         const float* __restrict__ Wih2, const float* __restrict__ Whh2,
                         const float* __restrict__ bih2, const float* __restrict__ bhh2,
                         const float* __restrict__ gamma, const float* __restrict__ beta,
                         const float* __restrict__ W1fc, const float* __restrict__ b1fc,
                         const float* __restrict__ W2fc, const float* __restrict__ b2fc,
                         float* __restrict__ out)
{
    // A1: [x(0:16) | h1(16:144) | zero pad(144:160)], stride 168 halves (bank-safe)
    // A2: [h1(0:128) | h2(128:192)], stride 200 halves
    __shared__ _Float16 A1[BT][168];
    __shared__ _Float16 A2[BT][200];
    __shared__ _Float16 bf2l[4 * 4 * 6 * 64 * 8];   // L2 B-frags, pre-packed, 96 KB
    __shared__ float h2f[BT][68];
    __shared__ float nrm[BT][68];

    const int tid  = threadIdx.x;
    const int lane = tid & 63;
    const int w    = tid >> 6;     // wave 0..7
    const int lrow = lane & 15;    // A-row / B-col index
    const int lgrp = lane >> 4;    // 0..3 (K-group; D rows lgrp*4+j)

    // ---------- persistent L1 weight fragments in VGPRs ----------
    // wave w owns h-indices [w*16, w*16+16) for ALL 4 gates -> i,f,g,o co-located per lane
    half8 bf1[4][5];
    float bias1[4];
#pragma unroll
    for (int g = 0; g < 4; ++g) {
        const int n = g * 128 + w * 16 + lrow;      // gate-major row of Wcat1
        bias1[g] = bih1[n] + bhh1[n];
#pragma unroll
        for (int ch = 0; ch < 5; ++ch) {
            half8 v;
#pragma unroll
            for (int j = 0; j < 8; ++j) {
                const int k = ch * 32 + lgrp * 8 + j;   // K = [x(16) | h1(128) | pad(16)]
                float t = 0.0f;
                if (k < 16)        t = Wih1[n * 16 + k];
                else if (k < 144)  t = Whh1[n * 128 + (k - 16)];
                v[j] = (_Float16)t;
            }
            bf1[g][ch] = v;
        }
    }
    // ---------- L2 weight fragments -> LDS (saves ~96 VGPRs) ----------
    float bias2[4] = {0.f, 0.f, 0.f, 0.f};
    if (w < 4) {
#pragma unroll
        for (int g = 0; g < 4; ++g) {
            const int n = g * 64 + w * 16 + lrow;   // K = [h1(128) | h2(64)]
            bias2[g] = bih2[n] + bhh2[n];
#pragma unroll
            for (int ch = 0; ch < 6; ++ch) {
                half8 v;
#pragma unroll
                for (int j = 0; j < 8; ++j) {
                    const int k = ch * 32 + lgrp * 8 + j;
                    v[j] = (_Float16)((k < 128) ? Wih2[n * 128 + k]
                                                : Whh2[n * 64 + (k - 128)]);
                }
                ((half8*)bf2l)[((w * 4 + g) * 6 + ch) * 64 + lane] = v;
            }
        }
    }

    const int hh1 = w * 16 + lrow;          // L1 cell index owned by this lane
    const int hh2 = (w & 3) * 16 + lrow;    // L2 cell index (valid for w<4)

    for (int tile = 0; tile < TILES; ++tile) {
        const int b0 = (blockIdx.x * TILES + tile) * BT;
        __syncthreads();
        // init: zero h/pad region of A1, all of A2; stage x(t=0)
        for (int idx = tid; idx < BT * 152; idx += NTHREADS)
            A1[idx / 152][16 + idx % 152] = (_Float16)0.f;
        for (int idx = tid; idx < BT * 200; idx += NTHREADS)
            (&A2[0][0])[idx] = (_Float16)0.f;
        if (tid < 256) {
            const int m = tid >> 4, i = tid & 15;
            A1[m][i] = (_Float16)x[(size_t)(b0 + m) * (T_STEPS * 16) + i];
        }
        float c1r[4] = {0.f, 0.f, 0.f, 0.f};
        float c2r[4] = {0.f, 0.f, 0.f, 0.f};
        __syncthreads();

        half8 af1[5];
#pragma unroll
        for (int ch = 0; ch < 5; ++ch)
            af1[ch] = *(const half8*)&A1[lrow][ch * 32 + lgrp * 8];
        __syncthreads();

        for (int t = 0; t < T_STEPS; ++t) {
            // ---- phase A (all waves): L1 gates + state + h1 -> LDS ----
            f32x4 z[4];
#pragma unroll
            for (int g = 0; g < 4; ++g) {
                f32x4 acc = {0.f, 0.f, 0.f, 0.f};
#pragma unroll
                for (int ch = 0; ch < 5; ++ch)
                    acc = __builtin_amdgcn_mfma_f32_16x16x32_f16(af1[ch], bf1[g][ch], acc, 0, 0, 0);
                z[g] = acc;
            }
#pragma unroll
            for (int j = 0; j < 4; ++j) {
                const float iv = fast_sig (z[0][j] + bias1[0]);
                const float fv = fast_sig (z[1][j] + bias1[1]);
                const float gv = fast_tanh(z[2][j] + bias1[2]);
                const float ov = fast_sig (z[3][j] + bias1[3]);
                const float cn = fv * c1r[j] + iv * gv;
                c1r[j] = cn;
                const float h = ov * fast_tanh(cn);
                const _Float16 h16 = (_Float16)h;
                const int m = lgrp * 4 + j;           // D-row = batch row
                A1[m][16 + hh1] = h16;                // feeds next step's L1
                A2[m][hh1]      = h16;                // feeds this step's L2
            }
            __syncthreads();

            // ---- phase B: w<4 load L2 A-frags; w>=4 prefetch x(t+1) ----
            half8 af2[6];
            if (w < 4) {
#pragma unroll
                for (int ch = 0; ch < 6; ++ch)
                    af2[ch] = *(const half8*)&A2[lrow][ch * 32 + lgrp * 8];
            } else if (t + 1 < T_STEPS) {
                const int local = tid - 256;
                const int m = local >> 4, i = local & 15;
                A1[m][i] = (_Float16)x[(size_t)(b0 + m) * (T_STEPS * 16) + (t + 1) * 16 + i];
            }
            __syncthreads();

            // ---- phase C: w<4 L2 gates + state + h2; all waves reload af1(t+1) ----
            if (w < 4) {
                f32x4 z2[4];
#pragma unroll
                for (int g = 0; g < 4; ++g) {
                    f32x4 acc = {0.f, 0.f, 0.f, 0.f};
#pragma unroll
                    for (int ch = 0; ch < 6; ++ch) {
                        const half8 bfrag = ((const half8*)bf2l)[((w * 4 + g) * 6 + ch) * 64 + lane];
                        acc = __builtin_amdgcn_mfma_f32_16x16x32_f16(af2[ch], bfrag, acc, 0, 0, 0);
                    }
                    z2[g] = acc;
                }
#pragma unroll
                for (int j = 0; j < 4; ++j) {
                    const float iv = fast_sig (z2[0][j] + bias2[0]);
                    const float fv = fast_sig (z2[1][j] + bias2[1]);
                    const float gv = fast_tanh(z2[2][j] + bias2[2]);
                    const float ov = fast_sig (z2[3][j] + bias2[3]);
                    const float cn = fv * c2r[j] + iv * gv;
                    c2r[j] = cn;
                    const float h = ov * fast_tanh(cn);
                    const int m = lgrp * 4 + j;
                    A2[m][128 + hh2] = (_Float16)h;
                    if (t == T_STEPS - 1) h2f[m][hh2] = h;
                }
            }
            if (t + 1 < T_STEPS) {
#pragma unroll
                for (int ch = 0; ch < 5; ++ch)
                    af1[ch] = *(const half8*)&A1[lrow][ch * 32 + lgrp * 8];
            }
            __syncthreads();
        }

        // ---- epilogue: LayerNorm + FC1(relu) + FC2 ----
        if (tid < 256) {
            const int m = tid >> 4, q = tid & 15;
            const float v0 = h2f[m][q * 4 + 0];
            const float v1 = h2f[m][q * 4 + 1];
            const float v2 = h2f[m][q * 4 + 2];
            const float v3 = h2f[m][q * 4 + 3];
            float s = v0 + v1 + v2 + v3;
            s += __shfl_xor(s, 1); s += __shfl_xor(s, 2);
            s += __shfl_xor(s, 4); s += __shfl_xor(s, 8);
            const float mean = s * (1.0f / 64.0f);
            const float d0 = v0 - mean, d1 = v1 - mean, d2 = v2 - mean, d3 = v3 - mean;
            float vs = d0 * d0 + d1 * d1 + d2 * d2 + d3 * d3;
            vs += __shfl_xor(vs, 1); vs += __shfl_xor(vs, 2);
            vs += __shfl_xor(vs, 4); vs += __shfl_xor(vs, 8);
            const float rstd = rsqrtf(vs * (1.0f / 64.0f) + 1e-5f);
            const int i0 = q * 4;
            nrm[m][i0 + 0] = d0 * rstd * gamma[i0 + 0] + beta[i0 + 0];
            nrm[m][i0 + 1] = d1 * rstd * gamma[i0 + 1] + beta[i0 + 1];
            nrm[m][i0 + 2] = d2 * rstd * gamma[i0 + 2] + beta[i0 + 2];
            nrm[m][i0 + 3] = d3 * rstd * gamma[i0 + 3] + beta[i0 + 3];
        }
        __syncthreads();
        {
            const int m = tid >> 5, o = tid & 31;
            float acc = b1fc[o];
#pragma unroll 8
            for (int k = 0; k < 64; ++k) acc += nrm[m][k] * W1fc[o * 64 + k];
            const float hv = fmaxf(acc, 0.0f);
            float p = hv * W2fc[o];
            p += __shfl_xor(p, 1); p += __shfl_xor(p, 2);
            p += __shfl_xor(p, 4); p += __shfl_xor(p, 8); p += __shfl_xor(p, 16);
            if (o == 0) out[b0 + m] = p + b2fc[0];
        }
    }
}

extern "C" void kernel_launch(void* const* d_in, const int* in_sizes, int n_in,
                              void* d_out, int out_size, void* d_ws, size_t ws_size,
                              hipStream_t stream) {
    (void)in_sizes; (void)n_in; (void)d_ws; (void)ws_size; (void)out_size;
    const float* x_p    = (const float*)d_in[0];
    const float* Wih1_p = (const float*)d_in[1];
    const float* Whh1_p = (const float*)d_in[2];
    const float* bih1_p = (const float*)d_in[3];
    const float* bhh1_p = (const float*)d_in[4];
    const float* Wih2_p = (const float*)d_in[5];
    const float* Whh2_p = (const float*)d_in[6];
    const float* bih2_p = (const float*)d_in[7];
    const float* bhh2_p = (const float*)d_in[8];
    const float* gamma_p = (const float*)d_in[9];
    const float* beta_p  = (const float*)d_in[10];
    const float* W1_p   = (const float*)d_in[11];
    const float* b1_p   = (const float*)d_in[12];
    const float* W2_p   = (const float*)d_in[13];
    const float* b2_p   = (const float*)d_in[14];
    float* out_p = (float*)d_out;

    dim3 grid(8192 / (BT * TILES));   // 256 blocks, one per CU
    dim3 block(NTHREADS);
    stacked_lstm_kernel<<<grid, block, 0, stream>>>(
        x_p, Wih1_p, Whh1_p, bih1_p, bhh1_p,
        Wih2_p, Whh2_p, bih2_p, bhh2_p,
        gamma_p, beta_p, W1_p, b1_p, W2_p, b2_p, out_p);
}